// Round 10
// baseline (260.115 us; speedup 1.0000x reference)
//
#include <hip/hip_runtime.h>

// MHA forward: B=4, S=2048, D=1024, H=16, hd=64, causal+pad mask, scale=8.
// IO fp32; internal bf16 MFMA with fp32 accumulate.
// v9: attention on 32x32x16 MFMAs (2x FLOP per LDS byte), wave = 32 q-rows,
// 4-wave blocks, stripe-paired uniform grid (512 blocks, 3/CU). Double-buffered
// XOR-swizzled K/V staging, S^T orientation (reg-quad = 4 keys -> b64 P-pack),
// unnormalized softmax, mask folded into V-zeroing + mask-vector lsum MFMA.
// GEMM v8 unchanged (BK=64, additive bank swizzle, conflict-free).

typedef __attribute__((ext_vector_type(8))) short bf16x8;
typedef __attribute__((ext_vector_type(8))) unsigned short u16x8;
typedef __attribute__((ext_vector_type(4))) unsigned short u16x4;
typedef __attribute__((ext_vector_type(4))) float f32x4;
typedef __attribute__((ext_vector_type(16))) float f32x16;

#define MFMA16 __builtin_amdgcn_mfma_f32_16x16x32_bf16
#define MFMA32 __builtin_amdgcn_mfma_f32_32x32x16_bf16

#define GLDS(gp, lp) __builtin_amdgcn_global_load_lds( \
    (const __attribute__((address_space(1))) unsigned int*)(gp), \
    (__attribute__((address_space(3))) unsigned int*)(lp), 16, 0, 0)

__device__ __forceinline__ unsigned short f2bf(float f) {
    union { float f; unsigned int u; } v; v.f = f;
    unsigned int r = v.u + 0x7fffu + ((v.u >> 16) & 1u);
    return (unsigned short)(r >> 16);
}

// bx<4096: fp32->bf16 x-convert (+mask->bf16 in first 32 blocks).
// bx>=4096: weight transposes (w_qkv 1024x3072, w_out 1024x1024).
__global__ void k_prep(const float* __restrict__ x, unsigned short* __restrict__ xb,
                       const int* __restrict__ mask, unsigned short* __restrict__ mb,
                       const float* __restrict__ wqkv, unsigned short* __restrict__ w1t,
                       const float* __restrict__ wout, unsigned short* __restrict__ w2t) {
    __shared__ float tile[32][33];
    const int bx = blockIdx.x;
    if (bx < 4096) {
        size_t i = ((size_t)bx * 256 + threadIdx.x) * 8;
        float4 f0 = *(const float4*)(x + i);
        float4 f1 = *(const float4*)(x + i + 4);
        u16x8 v;
        v[0] = f2bf(f0.x); v[1] = f2bf(f0.y); v[2] = f2bf(f0.z); v[3] = f2bf(f0.w);
        v[4] = f2bf(f1.x); v[5] = f2bf(f1.y); v[6] = f2bf(f1.z); v[7] = f2bf(f1.w);
        *(u16x8*)(xb + i) = v;
        if (bx < 32) {
            int j = bx * 256 + threadIdx.x;
            mb[j] = mask[j] ? (unsigned short)0x3F80 : (unsigned short)0;
        }
    } else {
        const int b2 = bx - 4096;
        const int cb = b2 & 127, rb = b2 >> 7;
        const float* in = (cb < 96) ? wqkv : wout;
        unsigned short* out = (cb < 96) ? w1t : w2t;
        const int C = (cb < 96) ? 3072 : 1024;
        const int c0 = ((cb < 96) ? cb : cb - 96) * 32;
        const int r0 = rb * 32;
        int tx = threadIdx.x & 31, ty = threadIdx.x >> 5;
        for (int i = ty; i < 32; i += 8)
            tile[i][tx] = in[(size_t)(r0 + i) * C + (c0 + tx)];
        __syncthreads();
        for (int i = ty; i < 32; i += 8)
            out[(size_t)(c0 + i) * 1024 + (r0 + tx)] = f2bf(tile[tx][i]);
    }
}

// C[M][N] = A[M][K] * Bt[N][K]^T.  128x128 tile, BK=64, swizzled LDS (v8, unchanged).
template <int MODE>
__global__ __launch_bounds__(256) void k_gemm_bt(
    const unsigned short* __restrict__ Ab,
    const unsigned short* __restrict__ Bt,
    float* __restrict__ Cf,
    unsigned short* __restrict__ qb,
    unsigned short* __restrict__ kb,
    unsigned short* __restrict__ vt,
    const int* __restrict__ mask,
    int N, int K)
{
    __shared__ __align__(16) unsigned short la[128 * 64];
    __shared__ __align__(16) unsigned short lb[128 * 64];
    const int t = threadIdx.x;
    const int m0 = blockIdx.y * 128, n0 = blockIdx.x * 128;
    const int w = t >> 6, lane = t & 63;
    const int wm = (w & 1) * 64, wn = (w >> 1) * 64;
    const int lr = lane & 15, lq = lane >> 4;
    const int lr7 = lr & 7;
    const int rowb = lane >> 3;
    const int g8 = (((lane & 7) - rowb) & 7) * 8;

    f32x4 acc[4][4];
    for (int i = 0; i < 4; ++i)
        for (int j = 0; j < 4; ++j)
            acc[i][j] = (f32x4){0.f, 0.f, 0.f, 0.f};

    for (int k0 = 0; k0 < K; k0 += 64) {
        #pragma unroll
        for (int r = 0; r < 4; ++r) {
            const int rg = w * 8 + r * 32;
            GLDS(&Ab[(size_t)(m0 + rg + rowb) * K + k0 + g8], &la[rg * 64]);
            GLDS(&Bt[(size_t)(n0 + rg + rowb) * K + k0 + g8], &lb[rg * 64]);
        }
        __syncthreads();
        #pragma unroll
        for (int ks = 0; ks < 2; ++ks) {
            const int pa = ((ks * 4 + lq + lr7) & 7) * 8;
            bf16x8 af[4], bg[4];
            #pragma unroll
            for (int i = 0; i < 4; ++i) {
                af[i] = *(const bf16x8*)&la[(wm + i * 16 + lr) * 64 + pa];
                bg[i] = *(const bf16x8*)&lb[(wn + i * 16 + lr) * 64 + pa];
            }
            #pragma unroll
            for (int i = 0; i < 4; ++i)
                #pragma unroll
                for (int j = 0; j < 4; ++j)
                    acc[i][j] = MFMA16(af[i], bg[j], acc[i][j], 0, 0, 0);
        }
        __syncthreads();
    }

    const float QSCALE = 0.18033688f;  // log2(e)/8, folded into Q
    if (MODE == 0) {
        for (int i = 0; i < 4; ++i)
            for (int j = 0; j < 4; ++j)
                for (int r = 0; r < 4; ++r) {
                    int row = m0 + wm + i * 16 + lq * 4 + r;
                    int col = n0 + wn + j * 16 + lr;
                    Cf[(size_t)row * N + col] = acc[i][j][r];
                }
    } else {
        const int which = n0 >> 10;
        if (which < 2) {
            unsigned short* dst = which ? kb : qb;
            const float sc = which ? 1.0f : QSCALE;
            for (int i = 0; i < 4; ++i)
                for (int j = 0; j < 4; ++j)
                    for (int r = 0; r < 4; ++r) {
                        int row = m0 + wm + i * 16 + lq * 4 + r;
                        int col = n0 + wn + j * 16 + lr;
                        int h = (col >> 6) & 15, d = col & 63;
                        int b = row >> 11, s = row & 2047;
                        dst[((size_t)(b * 16 + h) * 2048 + s) * 64 + d] = f2bf(acc[i][j][r] * sc);
                    }
        } else {
            for (int i = 0; i < 4; ++i) {
                int s0 = m0 + wm + i * 16 + lq * 4;
                int b = s0 >> 11, s = s0 & 2047;
                int4 m4 = *(const int4*)&mask[b * 2048 + s];
                for (int j = 0; j < 4; ++j) {
                    int col = n0 + wn + j * 16 + lr;
                    int h = (col >> 6) & 15, d = col & 63;
                    u16x4 pv;
                    pv[0] = m4.x ? f2bf(acc[i][j][0]) : (unsigned short)0;
                    pv[1] = m4.y ? f2bf(acc[i][j][1]) : (unsigned short)0;
                    pv[2] = m4.z ? f2bf(acc[i][j][2]) : (unsigned short)0;
                    pv[3] = m4.w ? f2bf(acc[i][j][3]) : (unsigned short)0;
                    *(u16x4*)&vt[((size_t)(b * 16 + h) * 64 + d) * 2048 + s] = pv;
                }
            }
        }
    }
}

// Flash attention v9 (32x32x16 MFMA). grid = (8, B*H); block 256 = 4 waves;
// wave = 32 q-rows; two passes over stripes (p, 15-p) => uniform 34 chunks.
// S^T = K.Q^T per 32-key tile: A=K[key][d], B=Q^T; C/D: col=q=lane&31,
// row=key=(reg&3)+8*(reg>>2)+4*(lane>>5). Reg-quad = 4 consecutive keys -> b64 pack.
// PV: A=P[q][key] (b128 from plds), B=V[key][d] (from vt_lds), +mask-vec lsum.
__global__ __launch_bounds__(256, 3) void k_attn(
    const unsigned short* __restrict__ qb,
    const unsigned short* __restrict__ kb,
    const unsigned short* __restrict__ vt,
    const unsigned short* __restrict__ maskbg,
    unsigned short* __restrict__ ao)
{
    __shared__ __align__(16) unsigned short kt_lds[2][64 * 64];  // [key][d], 16B blk p = g ^ (key&7)
    __shared__ __align__(16) unsigned short vt_lds[2][64 * 64];  // [d][key], 16B blk p = g ^ (d&7)
    __shared__ __align__(16) unsigned short plds[4][32 * 72];    // P[q][key] per wave, stride 72

    const int t = threadIdx.x;
    const int w = t >> 6, lane = t & 63;
    const int l31 = lane & 31, lh = lane >> 5;     // 32-row index, half-select
    const int l7 = l31 & 7;
    const int bh = blockIdx.y, b = bh >> 4, h = bh & 15;

    const unsigned short* qp = qb + (size_t)bh * 2048 * 64;
    const unsigned short* kp = kb + (size_t)bh * 2048 * 64;
    const unsigned short* vp = vt + (size_t)bh * 64 * 2048;
    const unsigned short* mbg = maskbg + b * 2048;
    unsigned short* pw = plds[w];

    const int rowb = lane >> 3, c8 = lane & 7;
    const int sc8 = (c8 ^ rowb) * 8;               // XOR-swizzled source column block

    auto stage = [&](int c) {
        const int buf = c & 1;
        const int k0 = c * 64;
        #pragma unroll
        for (int r = 0; r < 2; ++r) {
            const int rg = 8 * (w + 4 * r);        // wave-uniform group base row
            const int row = rg + rowb;
            GLDS(&kp[(size_t)(k0 + row) * 64 + sc8], &kt_lds[buf][rg * 64]);
            GLDS(&vp[(size_t)row * 2048 + k0 + sc8], &vt_lds[buf][rg * 64]);
        }
    };

    for (int pass = 0; pass < 2; ++pass) {
        const int stripe = pass ? (15 - (int)blockIdx.x) : (int)blockIdx.x;
        const int q0w = stripe * 128 + w * 32;

        // Q B-frags: B[k=d][n=q]: n=l31 -> q, k=lh*8+j within 16-d step
        bf16x8 aq[4];
        #pragma unroll
        for (int ks = 0; ks < 4; ++ks)
            aq[ks] = *(const bf16x8*)&qp[(q0w + l31) * 64 + ks * 16 + lh * 8];

        f32x16 acc[2];
        f32x16 lacc;
        #pragma unroll
        for (int r = 0; r < 16; ++r) { acc[0][r] = 0.f; acc[1][r] = 0.f; lacc[r] = 0.f; }

        const int nch = 2 * (stripe + 1);
        stage(0);
        for (int c = 0; c < nch; ++c) {
            __syncthreads();                 // staging of chunk c complete
            if (c + 1 < nch) stage(c + 1);   // async prefetch overlaps compute(c)
            const int k0 = c * 64;
            if (k0 < q0w + 32) {             // wave-uniform causal skip (rows q0w..q0w+31)
                const unsigned short* kt = kt_lds[c & 1];
                const unsigned short* vtl = vt_lds[c & 1];
                const bool causal = (k0 + 63 > q0w);
                // mask B-frags hoisted (global loads overlap QK/exp)
                bf16x8 mbf[4];
                #pragma unroll
                for (int ks = 0; ks < 4; ++ks)
                    mbf[ks] = *(const bf16x8*)&mbg[k0 + ks * 16 + lh * 8];

                // S^T per 32-key tile
                #pragma unroll
                for (int kt2 = 0; kt2 < 2; ++kt2) {
                    f32x16 s;
                    #pragma unroll
                    for (int r = 0; r < 16; ++r) s[r] = 0.f;
                    #pragma unroll
                    for (int ks = 0; ks < 4; ++ks) {
                        const int kb16 = ((ks * 2 + lh) ^ l7) * 8;   // swizzled phys block
                        bf16x8 kf = *(const bf16x8*)&kt[(kt2 * 32 + l31) * 64 + kb16];
                        s = MFMA32(kf, aq[ks], s, 0, 0, 0);
                    }
                    unsigned int u[16];
                    #pragma unroll
                    for (int r = 0; r < 16; ++r) {
                        float scv = s[r];
                        if (causal) {
                            int key = k0 + kt2 * 32 + (r & 3) + 8 * (r >> 2) + 4 * lh;
                            scv = (key <= q0w + l31) ? scv : -3.0e38f;
                        }
                        float p = __builtin_amdgcn_exp2f(scv);
                        union { float f; unsigned int u; } cv; cv.f = p;
                        u[r] = cv.u;
                    }
                    #pragma unroll
                    for (int g = 0; g < 4; ++g) {
                        uint2 pk;   // reg quad = keys {base..base+3}, truncating bf16 pack
                        pk.x = __builtin_amdgcn_perm(u[4 * g + 1], u[4 * g], 0x07060302u);
                        pk.y = __builtin_amdgcn_perm(u[4 * g + 3], u[4 * g + 2], 0x07060302u);
                        *(uint2*)&pw[l31 * 72 + kt2 * 32 + g * 8 + 4 * lh] = pk;
                    }
                }
                // O += P.V ; l += P.maskb  (P A-frag b128, same-wave LDS)
                #pragma unroll
                for (int ks = 0; ks < 4; ++ks) {
                    bf16x8 pf = *(const bf16x8*)&pw[l31 * 72 + ks * 16 + lh * 8];
                    const int vb16 = ((ks * 2 + lh) ^ l7) * 8;
                    #pragma unroll
                    for (int j = 0; j < 2; ++j) {
                        bf16x8 vf = *(const bf16x8*)&vtl[(j * 32 + l31) * 64 + vb16];
                        acc[j] = MFMA32(pf, vf, acc[j], 0, 0, 0);
                    }
                    lacc = MFMA32(pf, mbf[ks], lacc, 0, 0, 0);
                }
            }
        }

        #pragma unroll
        for (int r = 0; r < 16; ++r) {
            float inv = 1.0f / fmaxf(lacc[r], 1e-30f);
            int qq = q0w + (r & 3) + 8 * (r >> 2) + 4 * lh;
            #pragma unroll
            for (int j = 0; j < 2; ++j) {
                int d = j * 32 + l31;
                ao[(size_t)(b * 2048 + qq) * 1024 + h * 64 + d] = f2bf(acc[j][r] * inv);
            }
        }
        __syncthreads();   // buffers safe before next pass's stage(0)
    }
}

extern "C" void kernel_launch(void* const* d_in, const int* in_sizes, int n_in,
                              void* d_out, int out_size, void* d_ws, size_t ws_size,
                              hipStream_t stream)
{
    const float* x    = (const float*)d_in[0];
    const int*   mask = (const int*)d_in[1];
    const float* wqkv = (const float*)d_in[2];
    const float* wout = (const float*)d_in[3];
    float* out = (float*)d_out;

    const size_t NEED = ((size_t)8192 * 1024 + (size_t)3072 * 1024 + (size_t)1024 * 1024 +
                         3 * (size_t)64 * 2048 * 64 + (size_t)8192 * 1024 + 8192) * 2;
    if (ws_size < NEED) return;

    char* ws = (char*)d_ws;
    unsigned short* xb  = (unsigned short*)ws; ws += (size_t)8192 * 1024 * 2;
    unsigned short* w1t = (unsigned short*)ws; ws += (size_t)3072 * 1024 * 2;
    unsigned short* w2t = (unsigned short*)ws; ws += (size_t)1024 * 1024 * 2;
    unsigned short* qb  = (unsigned short*)ws; ws += (size_t)64 * 2048 * 64 * 2;
    unsigned short* kb  = (unsigned short*)ws; ws += (size_t)64 * 2048 * 64 * 2;
    unsigned short* vt  = (unsigned short*)ws; ws += (size_t)64 * 64 * 2048 * 2;
    unsigned short* ao  = (unsigned short*)ws; ws += (size_t)8192 * 1024 * 2;
    unsigned short* mbg = (unsigned short*)ws; ws += (size_t)8192 * 2;

    k_prep<<<dim3(8192), 256, 0, stream>>>(x, xb, mask, mbg, wqkv, w1t, wout, w2t);
    k_gemm_bt<1><<<dim3(24, 64), 256, 0, stream>>>(xb, w1t, nullptr, qb, kb, vt, mask, 3072, 1024);
    k_attn<<<dim3(8, 64), 256, 0, stream>>>(qb, kb, vt, mbg, ao);
    k_gemm_bt<0><<<dim3(8, 64), 256, 0, stream>>>(ao, w2t, out, nullptr, nullptr, nullptr, nullptr, 1024, 1024);
}

// Round 11
// 252.726 us; speedup vs baseline: 1.0292x; 1.0292x over previous
//
#include <hip/hip_runtime.h>

// MHA forward: B=4, S=2048, D=1024, H=16, hd=64, causal+pad mask, scale=8.
// IO fp32; internal bf16 MFMA with fp32 accumulate.
// v11: attention back on 16x16 MFMA (v7 body). Grid (64 bh, 16 pairs): XCD = bh%8
// pins each head's K/V to one XCD's L2 (8 heads x 512 KB = 4 MB = L2). 1024 uniform
// blocks (4 waves x 16 q, 64-q stripes paired p/31-p = 66 chunks), 32-key chunks,
// double-buffered GLDS staging, conflict-audited LDS layouts, unnormalized softmax,
// mask folded into V-zeroing + mask-vector lsum MFMA. GEMM v8 unchanged.

typedef __attribute__((ext_vector_type(8))) short bf16x8;
typedef __attribute__((ext_vector_type(8))) unsigned short u16x8;
typedef __attribute__((ext_vector_type(4))) unsigned short u16x4;
typedef __attribute__((ext_vector_type(4))) float f32x4;

#define MFMA16 __builtin_amdgcn_mfma_f32_16x16x32_bf16

#define GLDS(gp, lp) __builtin_amdgcn_global_load_lds( \
    (const __attribute__((address_space(1))) unsigned int*)(gp), \
    (__attribute__((address_space(3))) unsigned int*)(lp), 16, 0, 0)

__device__ __forceinline__ unsigned short f2bf(float f) {
    union { float f; unsigned int u; } v; v.f = f;
    unsigned int r = v.u + 0x7fffu + ((v.u >> 16) & 1u);
    return (unsigned short)(r >> 16);
}

// bx<4096: fp32->bf16 x-convert (+mask->bf16 in first 32 blocks).
// bx>=4096: weight transposes (w_qkv 1024x3072, w_out 1024x1024).
__global__ void k_prep(const float* __restrict__ x, unsigned short* __restrict__ xb,
                       const int* __restrict__ mask, unsigned short* __restrict__ mb,
                       const float* __restrict__ wqkv, unsigned short* __restrict__ w1t,
                       const float* __restrict__ wout, unsigned short* __restrict__ w2t) {
    __shared__ float tile[32][33];
    const int bx = blockIdx.x;
    if (bx < 4096) {
        size_t i = ((size_t)bx * 256 + threadIdx.x) * 8;
        float4 f0 = *(const float4*)(x + i);
        float4 f1 = *(const float4*)(x + i + 4);
        u16x8 v;
        v[0] = f2bf(f0.x); v[1] = f2bf(f0.y); v[2] = f2bf(f0.z); v[3] = f2bf(f0.w);
        v[4] = f2bf(f1.x); v[5] = f2bf(f1.y); v[6] = f2bf(f1.z); v[7] = f2bf(f1.w);
        *(u16x8*)(xb + i) = v;
        if (bx < 32) {
            int j = bx * 256 + threadIdx.x;
            mb[j] = mask[j] ? (unsigned short)0x3F80 : (unsigned short)0;
        }
    } else {
        const int b2 = bx - 4096;
        const int cb = b2 & 127, rb = b2 >> 7;
        const float* in = (cb < 96) ? wqkv : wout;
        unsigned short* out = (cb < 96) ? w1t : w2t;
        const int C = (cb < 96) ? 3072 : 1024;
        const int c0 = ((cb < 96) ? cb : cb - 96) * 32;
        const int r0 = rb * 32;
        int tx = threadIdx.x & 31, ty = threadIdx.x >> 5;
        for (int i = ty; i < 32; i += 8)
            tile[i][tx] = in[(size_t)(r0 + i) * C + (c0 + tx)];
        __syncthreads();
        for (int i = ty; i < 32; i += 8)
            out[(size_t)(c0 + i) * 1024 + (r0 + tx)] = f2bf(tile[tx][i]);
    }
}

// C[M][N] = A[M][K] * Bt[N][K]^T.  128x128 tile, BK=64, swizzled LDS (v8, unchanged).
template <int MODE>
__global__ __launch_bounds__(256) void k_gemm_bt(
    const unsigned short* __restrict__ Ab,
    const unsigned short* __restrict__ Bt,
    float* __restrict__ Cf,
    unsigned short* __restrict__ qb,
    unsigned short* __restrict__ kb,
    unsigned short* __restrict__ vt,
    const int* __restrict__ mask,
    int N, int K)
{
    __shared__ __align__(16) unsigned short la[128 * 64];
    __shared__ __align__(16) unsigned short lb[128 * 64];
    const int t = threadIdx.x;
    const int m0 = blockIdx.y * 128, n0 = blockIdx.x * 128;
    const int w = t >> 6, lane = t & 63;
    const int wm = (w & 1) * 64, wn = (w >> 1) * 64;
    const int lr = lane & 15, lq = lane >> 4;
    const int lr7 = lr & 7;
    const int rowb = lane >> 3;
    const int g8 = (((lane & 7) - rowb) & 7) * 8;

    f32x4 acc[4][4];
    for (int i = 0; i < 4; ++i)
        for (int j = 0; j < 4; ++j)
            acc[i][j] = (f32x4){0.f, 0.f, 0.f, 0.f};

    for (int k0 = 0; k0 < K; k0 += 64) {
        #pragma unroll
        for (int r = 0; r < 4; ++r) {
            const int rg = w * 8 + r * 32;
            GLDS(&Ab[(size_t)(m0 + rg + rowb) * K + k0 + g8], &la[rg * 64]);
            GLDS(&Bt[(size_t)(n0 + rg + rowb) * K + k0 + g8], &lb[rg * 64]);
        }
        __syncthreads();
        #pragma unroll
        for (int ks = 0; ks < 2; ++ks) {
            const int pa = ((ks * 4 + lq + lr7) & 7) * 8;
            bf16x8 af[4], bg[4];
            #pragma unroll
            for (int i = 0; i < 4; ++i) {
                af[i] = *(const bf16x8*)&la[(wm + i * 16 + lr) * 64 + pa];
                bg[i] = *(const bf16x8*)&lb[(wn + i * 16 + lr) * 64 + pa];
            }
            #pragma unroll
            for (int i = 0; i < 4; ++i)
                #pragma unroll
                for (int j = 0; j < 4; ++j)
                    acc[i][j] = MFMA16(af[i], bg[j], acc[i][j], 0, 0, 0);
        }
        __syncthreads();
    }

    const float QSCALE = 0.18033688f;  // log2(e)/8, folded into Q
    if (MODE == 0) {
        for (int i = 0; i < 4; ++i)
            for (int j = 0; j < 4; ++j)
                for (int r = 0; r < 4; ++r) {
                    int row = m0 + wm + i * 16 + lq * 4 + r;
                    int col = n0 + wn + j * 16 + lr;
                    Cf[(size_t)row * N + col] = acc[i][j][r];
                }
    } else {
        const int which = n0 >> 10;
        if (which < 2) {
            unsigned short* dst = which ? kb : qb;
            const float sc = which ? 1.0f : QSCALE;
            for (int i = 0; i < 4; ++i)
                for (int j = 0; j < 4; ++j)
                    for (int r = 0; r < 4; ++r) {
                        int row = m0 + wm + i * 16 + lq * 4 + r;
                        int col = n0 + wn + j * 16 + lr;
                        int h = (col >> 6) & 15, d = col & 63;
                        int b = row >> 11, s = row & 2047;
                        dst[((size_t)(b * 16 + h) * 2048 + s) * 64 + d] = f2bf(acc[i][j][r] * sc);
                    }
        } else {
            for (int i = 0; i < 4; ++i) {
                int s0 = m0 + wm + i * 16 + lq * 4;
                int b = s0 >> 11, s = s0 & 2047;
                int4 m4 = *(const int4*)&mask[b * 2048 + s];
                for (int j = 0; j < 4; ++j) {
                    int col = n0 + wn + j * 16 + lr;
                    int h = (col >> 6) & 15, d = col & 63;
                    u16x4 pv;
                    pv[0] = m4.x ? f2bf(acc[i][j][0]) : (unsigned short)0;
                    pv[1] = m4.y ? f2bf(acc[i][j][1]) : (unsigned short)0;
                    pv[2] = m4.z ? f2bf(acc[i][j][2]) : (unsigned short)0;
                    pv[3] = m4.w ? f2bf(acc[i][j][3]) : (unsigned short)0;
                    *(u16x4*)&vt[((size_t)(b * 16 + h) * 64 + d) * 2048 + s] = pv;
                }
            }
        }
    }
}

// Flash attention v11. grid = (64 bh, 16 pairs); block 256 = 4 waves x 16 q.
// XCD = bh%8 -> per-head K/V pinned to one XCD's L2. 64-q stripes, pairs (p,31-p)
// => uniform 66 chunk-stages. 32-key chunks, double-buffered GLDS staging.
__global__ __launch_bounds__(256, 4) void k_attn(
    const unsigned short* __restrict__ qb,
    const unsigned short* __restrict__ kb,
    const unsigned short* __restrict__ vt,
    const unsigned short* __restrict__ maskbg,
    unsigned short* __restrict__ ao)
{
    __shared__ __align__(16) unsigned short kt_lds[2][32 * 64];  // [key][d], blk p = g ^ (key&7)
    __shared__ __align__(16) unsigned short vt_lds[2][64 * 32];  // [d][key], natural (conflict-free)
    __shared__ __align__(16) unsigned short plds[4][16 * 40];    // P[q][key] per wave, stride 40

    const int t = threadIdx.x;
    const int w = t >> 6, lane = t & 63;
    const int lr = lane & 15, lq = lane >> 4;
    const int lr7 = lr & 7;
    const int bh = blockIdx.x, b = bh >> 4, h = bh & 15;

    const unsigned short* qp = qb + (size_t)bh * 2048 * 64;
    const unsigned short* kp = kb + (size_t)bh * 2048 * 64;
    const unsigned short* vp = vt + (size_t)bh * 64 * 2048;
    const unsigned short* mbg = maskbg + b * 2048;
    unsigned short* pw = plds[w];

    // staging lane maps: K = 8 rows x 8 swizzled 16B blocks per wave; V = 16 rows x 4 blocks
    const int krow = lane >> 3, kblk = lane & 7;
    const int kcol = (kblk ^ krow) * 8;              // phys p holds global blk p ^ (row&7)
    const int vrow = lane >> 2, vcol = (lane & 3) * 8;

    auto stage = [&](int c) {
        const int buf = c & 1;
        const int k0 = c * 32;
        GLDS(&kp[(size_t)(k0 + 8 * w + krow) * 64 + kcol], &kt_lds[buf][(8 * w) * 64]);
        GLDS(&vp[(size_t)(16 * w + vrow) * 2048 + k0 + vcol], &vt_lds[buf][(16 * w) * 32]);
    };

    const int pa0 = (lq ^ lr7) * 8;                  // K frag phys blocks (row%8 == lr7)
    const int pa1 = ((4 + lq) ^ lr7) * 8;

    for (int pass = 0; pass < 2; ++pass) {
        const int stripe = pass ? (31 - (int)blockIdx.y) : (int)blockIdx.y;
        const int q0w = stripe * 64 + w * 16;

        // Q B-frags: n=lr -> q, k=lq*8+j -> d
        bf16x8 aq0 = *(const bf16x8*)&qp[(q0w + lr) * 64 + lq * 8];
        bf16x8 aq1 = *(const bf16x8*)&qp[(q0w + lr) * 64 + 32 + lq * 8];

        f32x4 acc[4], lacc;
        lacc = (f32x4){0.f, 0.f, 0.f, 0.f};
        #pragma unroll
        for (int j = 0; j < 4; ++j) acc[j] = (f32x4){0.f, 0.f, 0.f, 0.f};

        const int nch = 2 * (stripe + 1);
        stage(0);
        for (int c = 0; c < nch; ++c) {
            __syncthreads();                 // staging of chunk c complete
            if (c + 1 < nch) stage(c + 1);   // async prefetch overlaps compute(c)
            const int k0 = c * 32;
            if (k0 < q0w + 16) {             // wave-uniform causal skip
                const unsigned short* kt = kt_lds[c & 1];
                const unsigned short* vtl = vt_lds[c & 1];
                const bool causal = (k0 + 31 > q0w);
                // S^T = K.Q^T per 16-key tile; lane: q=lr, keys=ki*16+lq*4+r
                #pragma unroll
                for (int ki = 0; ki < 2; ++ki) {
                    bf16x8 kf0 = *(const bf16x8*)&kt[(ki * 16 + lr) * 64 + pa0];
                    bf16x8 kf1 = *(const bf16x8*)&kt[(ki * 16 + lr) * 64 + pa1];
                    f32x4 s = (f32x4){0.f, 0.f, 0.f, 0.f};
                    s = MFMA16(kf0, aq0, s, 0, 0, 0);
                    s = MFMA16(kf1, aq1, s, 0, 0, 0);
                    unsigned int u[4];
                    #pragma unroll
                    for (int r = 0; r < 4; ++r) {
                        float scv = s[r];
                        if (causal) {
                            int key = k0 + ki * 16 + lq * 4 + r;
                            scv = (key <= q0w + lr) ? scv : -3.0e38f;
                        }
                        float p = __builtin_amdgcn_exp2f(scv);
                        union { float f; unsigned int u; } cv; cv.f = p;
                        u[r] = cv.u;
                    }
                    uint2 pk;   // truncating bf16 pack
                    pk.x = __builtin_amdgcn_perm(u[1], u[0], 0x07060302u);
                    pk.y = __builtin_amdgcn_perm(u[3], u[2], 0x07060302u);
                    *(uint2*)&pw[lr * 40 + ki * 16 + lq * 4] = pk;
                }
                // O += P.V ; l += P.maskb  (P A-frag b128, same-wave in-order DS)
                bf16x8 pf = *(const bf16x8*)&pw[lr * 40 + lq * 8];
                bf16x8 mb = *(const bf16x8*)&mbg[k0 + lq * 8];
                #pragma unroll
                for (int j = 0; j < 4; ++j) {
                    bf16x8 vf = *(const bf16x8*)&vtl[(j * 16 + lr) * 32 + lq * 8];
                    acc[j] = MFMA16(pf, vf, acc[j], 0, 0, 0);
                }
                lacc = MFMA16(pf, mb, lacc, 0, 0, 0);
            }
        }

        #pragma unroll
        for (int r = 0; r < 4; ++r) {
            float inv = 1.0f / fmaxf(lacc[r], 1e-30f);
            int row = q0w + lq * 4 + r;
            #pragma unroll
            for (int j = 0; j < 4; ++j) {
                int d = j * 16 + lr;
                ao[(size_t)(b * 2048 + row) * 1024 + h * 64 + d] = f2bf(acc[j][r] * inv);
            }
        }
        __syncthreads();   // buffers safe before next pass's stage(0)
    }
}

extern "C" void kernel_launch(void* const* d_in, const int* in_sizes, int n_in,
                              void* d_out, int out_size, void* d_ws, size_t ws_size,
                              hipStream_t stream)
{
    const float* x    = (const float*)d_in[0];
    const int*   mask = (const int*)d_in[1];
    const float* wqkv = (const float*)d_in[2];
    const float* wout = (const float*)d_in[3];
    float* out = (float*)d_out;

    const size_t NEED = ((size_t)8192 * 1024 + (size_t)3072 * 1024 + (size_t)1024 * 1024 +
                         3 * (size_t)64 * 2048 * 64 + (size_t)8192 * 1024 + 8192) * 2;
    if (ws_size < NEED) return;

    char* ws = (char*)d_ws;
    unsigned short* xb  = (unsigned short*)ws; ws += (size_t)8192 * 1024 * 2;
    unsigned short* w1t = (unsigned short*)ws; ws += (size_t)3072 * 1024 * 2;
    unsigned short* w2t = (unsigned short*)ws; ws += (size_t)1024 * 1024 * 2;
    unsigned short* qb  = (unsigned short*)ws; ws += (size_t)64 * 2048 * 64 * 2;
    unsigned short* kb  = (unsigned short*)ws; ws += (size_t)64 * 2048 * 64 * 2;
    unsigned short* vt  = (unsigned short*)ws; ws += (size_t)64 * 64 * 2048 * 2;
    unsigned short* ao  = (unsigned short*)ws; ws += (size_t)8192 * 1024 * 2;
    unsigned short* mbg = (unsigned short*)ws; ws += (size_t)8192 * 2;

    k_prep<<<dim3(8192), 256, 0, stream>>>(x, xb, mask, mbg, wqkv, w1t, wout, w2t);
    k_gemm_bt<1><<<dim3(24, 64), 256, 0, stream>>>(xb, w1t, nullptr, qb, kb, vt, mask, 3072, 1024);
    k_attn<<<dim3(64, 16), 256, 0, stream>>>(qb, kb, vt, mbg, ao);
    k_gemm_bt<0><<<dim3(8, 64), 256, 0, stream>>>(ao, w2t, out, nullptr, nullptr, nullptr, nullptr, 1024, 1024);
}

// Round 12
// 250.665 us; speedup vs baseline: 1.0377x; 1.0082x over previous
//
#include <hip/hip_runtime.h>

// MHA forward: B=4, S=2048, D=1024, H=16, hd=64, causal+pad mask, scale=8.
// IO fp32; internal bf16 MFMA with fp32 accumulate.
// v12 = R9's proven v7 attention body (512-thr blocks, 8 waves x 16 q, 64-key
// chunks, stripe pairs (p,15-p), double-buffered XOR-swizzled K/V staging)
// + R11's XCD pinning: grid (64 bh, 8 pairs) => linear%8 = bh%8 pins each
// head's K/V to one XCD L2 (FETCH 147->25 MB measured). GEMM v8 unchanged.

typedef __attribute__((ext_vector_type(8))) short bf16x8;
typedef __attribute__((ext_vector_type(8))) unsigned short u16x8;
typedef __attribute__((ext_vector_type(4))) unsigned short u16x4;
typedef __attribute__((ext_vector_type(4))) float f32x4;

#define MFMA16 __builtin_amdgcn_mfma_f32_16x16x32_bf16

#define GLDS(gp, lp) __builtin_amdgcn_global_load_lds( \
    (const __attribute__((address_space(1))) unsigned int*)(gp), \
    (__attribute__((address_space(3))) unsigned int*)(lp), 16, 0, 0)

__device__ __forceinline__ unsigned short f2bf(float f) {
    union { float f; unsigned int u; } v; v.f = f;
    unsigned int r = v.u + 0x7fffu + ((v.u >> 16) & 1u);
    return (unsigned short)(r >> 16);
}

// bx<4096: fp32->bf16 x-convert (+mask->bf16 in first 32 blocks).
// bx>=4096: weight transposes (w_qkv 1024x3072, w_out 1024x1024).
__global__ void k_prep(const float* __restrict__ x, unsigned short* __restrict__ xb,
                       const int* __restrict__ mask, unsigned short* __restrict__ mb,
                       const float* __restrict__ wqkv, unsigned short* __restrict__ w1t,
                       const float* __restrict__ wout, unsigned short* __restrict__ w2t) {
    __shared__ float tile[32][33];
    const int bx = blockIdx.x;
    if (bx < 4096) {
        size_t i = ((size_t)bx * 256 + threadIdx.x) * 8;
        float4 f0 = *(const float4*)(x + i);
        float4 f1 = *(const float4*)(x + i + 4);
        u16x8 v;
        v[0] = f2bf(f0.x); v[1] = f2bf(f0.y); v[2] = f2bf(f0.z); v[3] = f2bf(f0.w);
        v[4] = f2bf(f1.x); v[5] = f2bf(f1.y); v[6] = f2bf(f1.z); v[7] = f2bf(f1.w);
        *(u16x8*)(xb + i) = v;
        if (bx < 32) {
            int j = bx * 256 + threadIdx.x;
            mb[j] = mask[j] ? (unsigned short)0x3F80 : (unsigned short)0;
        }
    } else {
        const int b2 = bx - 4096;
        const int cb = b2 & 127, rb = b2 >> 7;
        const float* in = (cb < 96) ? wqkv : wout;
        unsigned short* out = (cb < 96) ? w1t : w2t;
        const int C = (cb < 96) ? 3072 : 1024;
        const int c0 = ((cb < 96) ? cb : cb - 96) * 32;
        const int r0 = rb * 32;
        int tx = threadIdx.x & 31, ty = threadIdx.x >> 5;
        for (int i = ty; i < 32; i += 8)
            tile[i][tx] = in[(size_t)(r0 + i) * C + (c0 + tx)];
        __syncthreads();
        for (int i = ty; i < 32; i += 8)
            out[(size_t)(c0 + i) * 1024 + (r0 + tx)] = f2bf(tile[tx][i]);
    }
}

// C[M][N] = A[M][K] * Bt[N][K]^T.  128x128 tile, BK=64, swizzled LDS (v8, unchanged).
template <int MODE>
__global__ __launch_bounds__(256) void k_gemm_bt(
    const unsigned short* __restrict__ Ab,
    const unsigned short* __restrict__ Bt,
    float* __restrict__ Cf,
    unsigned short* __restrict__ qb,
    unsigned short* __restrict__ kb,
    unsigned short* __restrict__ vt,
    const int* __restrict__ mask,
    int N, int K)
{
    __shared__ __align__(16) unsigned short la[128 * 64];
    __shared__ __align__(16) unsigned short lb[128 * 64];
    const int t = threadIdx.x;
    const int m0 = blockIdx.y * 128, n0 = blockIdx.x * 128;
    const int w = t >> 6, lane = t & 63;
    const int wm = (w & 1) * 64, wn = (w >> 1) * 64;
    const int lr = lane & 15, lq = lane >> 4;
    const int lr7 = lr & 7;
    const int rowb = lane >> 3;
    const int g8 = (((lane & 7) - rowb) & 7) * 8;

    f32x4 acc[4][4];
    for (int i = 0; i < 4; ++i)
        for (int j = 0; j < 4; ++j)
            acc[i][j] = (f32x4){0.f, 0.f, 0.f, 0.f};

    for (int k0 = 0; k0 < K; k0 += 64) {
        #pragma unroll
        for (int r = 0; r < 4; ++r) {
            const int rg = w * 8 + r * 32;
            GLDS(&Ab[(size_t)(m0 + rg + rowb) * K + k0 + g8], &la[rg * 64]);
            GLDS(&Bt[(size_t)(n0 + rg + rowb) * K + k0 + g8], &lb[rg * 64]);
        }
        __syncthreads();
        #pragma unroll
        for (int ks = 0; ks < 2; ++ks) {
            const int pa = ((ks * 4 + lq + lr7) & 7) * 8;
            bf16x8 af[4], bg[4];
            #pragma unroll
            for (int i = 0; i < 4; ++i) {
                af[i] = *(const bf16x8*)&la[(wm + i * 16 + lr) * 64 + pa];
                bg[i] = *(const bf16x8*)&lb[(wn + i * 16 + lr) * 64 + pa];
            }
            #pragma unroll
            for (int i = 0; i < 4; ++i)
                #pragma unroll
                for (int j = 0; j < 4; ++j)
                    acc[i][j] = MFMA16(af[i], bg[j], acc[i][j], 0, 0, 0);
        }
        __syncthreads();
    }

    const float QSCALE = 0.18033688f;  // log2(e)/8, folded into Q
    if (MODE == 0) {
        for (int i = 0; i < 4; ++i)
            for (int j = 0; j < 4; ++j)
                for (int r = 0; r < 4; ++r) {
                    int row = m0 + wm + i * 16 + lq * 4 + r;
                    int col = n0 + wn + j * 16 + lr;
                    Cf[(size_t)row * N + col] = acc[i][j][r];
                }
    } else {
        const int which = n0 >> 10;
        if (which < 2) {
            unsigned short* dst = which ? kb : qb;
            const float sc = which ? 1.0f : QSCALE;
            for (int i = 0; i < 4; ++i)
                for (int j = 0; j < 4; ++j)
                    for (int r = 0; r < 4; ++r) {
                        int row = m0 + wm + i * 16 + lq * 4 + r;
                        int col = n0 + wn + j * 16 + lr;
                        int h = (col >> 6) & 15, d = col & 63;
                        int b = row >> 11, s = row & 2047;
                        dst[((size_t)(b * 16 + h) * 2048 + s) * 64 + d] = f2bf(acc[i][j][r] * sc);
                    }
        } else {
            for (int i = 0; i < 4; ++i) {
                int s0 = m0 + wm + i * 16 + lq * 4;
                int b = s0 >> 11, s = s0 & 2047;
                int4 m4 = *(const int4*)&mask[b * 2048 + s];
                for (int j = 0; j < 4; ++j) {
                    int col = n0 + wn + j * 16 + lr;
                    int h = (col >> 6) & 15, d = col & 63;
                    u16x4 pv;
                    pv[0] = m4.x ? f2bf(acc[i][j][0]) : (unsigned short)0;
                    pv[1] = m4.y ? f2bf(acc[i][j][1]) : (unsigned short)0;
                    pv[2] = m4.z ? f2bf(acc[i][j][2]) : (unsigned short)0;
                    pv[3] = m4.w ? f2bf(acc[i][j][3]) : (unsigned short)0;
                    *(u16x4*)&vt[((size_t)(b * 16 + h) * 64 + d) * 2048 + s] = pv;
                }
            }
        }
    }
}

// Flash attention v12. grid = (64 bh, 8 pairs); block 512 = 8 waves x 16 q;
// two passes over stripes (p, 15-p) => uniform 34 chunk-stages per block.
// XCD = linear%8 = bh%8 -> per-head K/V pinned to one XCD's L2.
__global__ __launch_bounds__(512, 4) void k_attn(
    const unsigned short* __restrict__ qb,
    const unsigned short* __restrict__ kb,
    const unsigned short* __restrict__ vt,
    const unsigned short* __restrict__ maskbg,
    unsigned short* __restrict__ ao)
{
    __shared__ __align__(16) unsigned short kt_lds[2][64 * 64];  // [key][d], d-blocks XOR key&7
    __shared__ __align__(16) unsigned short vt_lds[2][64 * 64];  // [d][key], key-blocks XOR d&7
    __shared__ __align__(16) unsigned short plds[8][16 * 72];    // P[q][key] per wave, stride 72

    const int t = threadIdx.x;
    const int w = t >> 6, lane = t & 63;
    const int lr = lane & 15, lq = lane >> 4;
    const int lr7 = lr & 7;
    const int bh = blockIdx.x, b = bh >> 4, h = bh & 15;

    const unsigned short* qp = qb + (size_t)bh * 2048 * 64;
    const unsigned short* kp = kb + (size_t)bh * 2048 * 64;
    const unsigned short* vp = vt + (size_t)bh * 64 * 2048;
    const unsigned short* mbg = maskbg + b * 2048;
    unsigned short* pw = plds[w];

    const int rowb = lane >> 3, c8 = lane & 7;
    const int sc8 = (c8 ^ rowb) * 8;                 // XOR-swizzled source column block

    auto stage = [&](int c) {
        const int buf = c & 1;
        const int k0 = c * 64;
        const int rg = 8 * w;
        const int row = rg + rowb;
        GLDS(&kp[(size_t)(k0 + row) * 64 + sc8], &kt_lds[buf][rg * 64]);
        GLDS(&vp[(size_t)row * 2048 + k0 + sc8], &vt_lds[buf][rg * 64]);
    };

    for (int pass = 0; pass < 2; ++pass) {
        const int stripe = pass ? (15 - (int)blockIdx.y) : (int)blockIdx.y;
        const int q0w = stripe * 128 + w * 16;

        bf16x8 aq0 = *(const bf16x8*)&qp[(q0w + lr) * 64 + lq * 8];
        bf16x8 aq1 = *(const bf16x8*)&qp[(q0w + lr) * 64 + 32 + lq * 8];

        f32x4 acc[4], lacc;
        lacc = (f32x4){0.f, 0.f, 0.f, 0.f};
        #pragma unroll
        for (int j = 0; j < 4; ++j) acc[j] = (f32x4){0.f, 0.f, 0.f, 0.f};

        const int nch = 2 * (stripe + 1);
        stage(0);
        for (int c = 0; c < nch; ++c) {
            __syncthreads();
            if (c + 1 < nch) stage(c + 1);
            const int k0 = c * 64;
            if (k0 < q0w + 16) {
                const unsigned short* kt = kt_lds[c & 1];
                const unsigned short* vtl = vt_lds[c & 1];
                const bool causal = (k0 + 63 > q0w);
                const int kcol0 = (lq ^ lr7) * 8;
                const int kcol1 = ((4 + lq) ^ lr7) * 8;
                #pragma unroll
                for (int ki = 0; ki < 4; ++ki) {
                    bf16x8 kf0 = *(const bf16x8*)&kt[(ki * 16 + lr) * 64 + kcol0];
                    bf16x8 kf1 = *(const bf16x8*)&kt[(ki * 16 + lr) * 64 + kcol1];
                    f32x4 s = (f32x4){0.f, 0.f, 0.f, 0.f};
                    s = MFMA16(kf0, aq0, s, 0, 0, 0);
                    s = MFMA16(kf1, aq1, s, 0, 0, 0);
                    unsigned int u[4];
                    #pragma unroll
                    for (int r = 0; r < 4; ++r) {
                        float scv = s[r];
                        if (causal) {
                            int key = k0 + ki * 16 + lq * 4 + r;
                            int qq  = q0w + lr;
                            scv = (key <= qq) ? scv : -3.0e38f;
                        }
                        float p = __builtin_amdgcn_exp2f(scv);
                        union { float f; unsigned int u; } cv; cv.f = p;
                        u[r] = cv.u;
                    }
                    uint2 pk;
                    pk.x = __builtin_amdgcn_perm(u[1], u[0], 0x07060302u);
                    pk.y = __builtin_amdgcn_perm(u[3], u[2], 0x07060302u);
                    *(uint2*)&pw[lr * 72 + ki * 16 + lq * 4] = pk;
                }
                #pragma unroll
                for (int kc = 0; kc < 64; kc += 32) {
                    bf16x8 pf = *(const bf16x8*)&pw[lr * 72 + kc + lq * 8];
                    bf16x8 mb = *(const bf16x8*)&mbg[k0 + kc + lq * 8];
                    const int vcol = (((kc >> 3) + lq) ^ lr7) * 8;
                    #pragma unroll
                    for (int j = 0; j < 4; ++j) {
                        bf16x8 vf = *(const bf16x8*)&vtl[(j * 16 + lr) * 64 + vcol];
                        acc[j] = MFMA16(pf, vf, acc[j], 0, 0, 0);
                    }
                    lacc = MFMA16(pf, mb, lacc, 0, 0, 0);
                }
            }
        }

        #pragma unroll
        for (int r = 0; r < 4; ++r) {
            float inv = 1.0f / fmaxf(lacc[r], 1e-30f);
            int row = q0w + lq * 4 + r;
            #pragma unroll
            for (int j = 0; j < 4; ++j) {
                int d = j * 16 + lr;
                ao[(size_t)(b * 2048 + row) * 1024 + h * 64 + d] = f2bf(acc[j][r] * inv);
            }
        }
        __syncthreads();
    }
}

extern "C" void kernel_launch(void* const* d_in, const int* in_sizes, int n_in,
                              void* d_out, int out_size, void* d_ws, size_t ws_size,
                              hipStream_t stream)
{
    const float* x    = (const float*)d_in[0];
    const int*   mask = (const int*)d_in[1];
    const float* wqkv = (const float*)d_in[2];
    const float* wout = (const float*)d_in[3];
    float* out = (float*)d_out;

    const size_t NEED = ((size_t)8192 * 1024 + (size_t)3072 * 1024 + (size_t)1024 * 1024 +
                         3 * (size_t)64 * 2048 * 64 + (size_t)8192 * 1024 + 8192) * 2;
    if (ws_size < NEED) return;

    char* ws = (char*)d_ws;
    unsigned short* xb  = (unsigned short*)ws; ws += (size_t)8192 * 1024 * 2;
    unsigned short* w1t = (unsigned short*)ws; ws += (size_t)3072 * 1024 * 2;
    unsigned short* w2t = (unsigned short*)ws; ws += (size_t)1024 * 1024 * 2;
    unsigned short* qb  = (unsigned short*)ws; ws += (size_t)64 * 2048 * 64 * 2;
    unsigned short* kb  = (unsigned short*)ws; ws += (size_t)64 * 2048 * 64 * 2;
    unsigned short* vt  = (unsigned short*)ws; ws += (size_t)64 * 64 * 2048 * 2;
    unsigned short* ao  = (unsigned short*)ws; ws += (size_t)8192 * 1024 * 2;
    unsigned short* mbg = (unsigned short*)ws; ws += (size_t)8192 * 2;

    k_prep<<<dim3(8192), 256, 0, stream>>>(x, xb, mask, mbg, wqkv, w1t, wout, w2t);
    k_gemm_bt<1><<<dim3(24, 64), 256, 0, stream>>>(xb, w1t, nullptr, qb, kb, vt, mask, 3072, 1024);
    k_attn<<<dim3(64, 8), 512, 0, stream>>>(qb, kb, vt, mbg, ao);
    k_gemm_bt<0><<<dim3(8, 64), 256, 0, stream>>>(ao, w2t, out, nullptr, nullptr, nullptr, nullptr, 1024, 1024);
}